// Round 1
// baseline (190.993 us; speedup 1.0000x reference)
//
#include <hip/hip_runtime.h>

#define CHUNK 256
#define MM 50
#define KK 4
#define STATE (MM*KK)   // 200
#define ASTRIDE 51      // odd word stride for P0/P1 rows (full 32-bank spread)
#define SUP 32          // chunks per super-chunk
#define NSMAX 26        // max super-chunks (G<=832)
#define NSUB 8          // sub-chunks per chunk
#define SUBSZ 32        // events per sub-chunk
#define GMAX 1024

// Cross-block communication lives in device globals (.bss -> zeroed at module
// load). Flags are epoch-valued (DONE = ticket/G + 1), so repeated graph
// replays stay correct with NO per-iteration reset and NO init dispatch.
__device__ int      g_ticket;               // monotone across iterations
__device__ unsigned g_flag[GMAX];           // chunk-done flags
__device__ unsigned g_sflag[64];            // super-done flags
__device__ float    g_chunkB[GMAX * STATE];
__device__ float    g_superB[64 * STATE];

__device__ __forceinline__ unsigned short f2bf(float x) {
  unsigned u = __float_as_uint(x);
  u += 0x7fffu + ((u >> 16) & 1u);   // round-to-nearest-even
  return (unsigned short)(u >> 16);
}

__global__ __launch_bounds__(512) void hawkes_fused(
    const float* __restrict__ ti, const int* __restrict__ mi,
    const float* __restrict__ mu, const float* __restrict__ alpha,
    const float* __restrict__ gamma, float* __restrict__ out, int N, int G) {
  int tid = threadIdx.x;
  __shared__ int vid_s;
  __shared__ unsigned P0[MM * ASTRIDE];          // bf16x2 {k0,k1} of gamma_k*alpha
  __shared__ unsigned P1[MM * ASTRIDE];          // bf16x2 {k2,k3}
  __shared__ __align__(16) float4 Fj[CHUNK];     // exp(+gamma_k*(t_j - t_ref))
  __shared__ int   cj[CHUNK];
  __shared__ __align__(16) float Q[NSUB][STATE]; // sub-chunk buckets -> WB prefix
  __shared__ float red8[8];
  __shared__ float teL[SUP];                     // end times of chunks g0..g0+SUP-1
  __shared__ float tlast[NSMAX];                 // end times of supers 0..sup-1

  // ticket -> virtual block id in dispatch order (deadlock-free lookback)
  if (tid == 0) vid_s = atomicAdd(&g_ticket, 1);

  float gk0 = gamma[0], gk1 = gamma[1], gk2 = gamma[2], gk3 = gamma[3];

  for (int i = tid; i < NSUB * STATE; i += 512) ((float*)Q)[i] = 0.f;

  for (int idx = tid; idx < MM * MM; idx += 512) {
    int c = idx / MM, cp = idx - c * MM;
    float a0 = gk0 * alpha[idx];
    float a1 = gk1 * alpha[2500 + idx];
    float a2 = gk2 * alpha[5000 + idx];
    float a3 = gk3 * alpha[7500 + idx];
    P0[c * ASTRIDE + cp] = (unsigned)f2bf(a0) | ((unsigned)f2bf(a1) << 16);
    P1[c * ASTRIDE + cp] = (unsigned)f2bf(a2) | ((unsigned)f2bf(a3) << 16);
  }
  __syncthreads();   // vid ready (also Q zeroed, P staged)

  int tkt = vid_s;
  int epoch = tkt / G;
  int g = tkt - epoch * G;
  unsigned DONE = (unsigned)epoch + 1u;
  int l = g * CHUNK;
  int r = min(N, l + CHUNK);
  int cnt = r - l;
  int sup = g / SUP;
  int g0 = sup * SUP;
  int e = tid >> 1;    // event slot 0..255 (wave w <-> sub-chunk w)
  int h = tid & 1;     // half: 0 = low marks/even slots, 1 = high marks/odd slots

  // stage end-times for the direct prefix sums
  if (tid < SUP) {
    int c = g0 + tid;
    if (c < G) teL[tid] = ti[min(N, (c + 1) * CHUNK) - 1];
  } else if (tid >= 64 && tid < 64 + NSMAX) {
    int s = tid - 64;
    if (s < sup) tlast[s] = ti[min(N, (s + 1) * SUP * CHUNK) - 1];
  }

  float t_ref = ti[(g == 0) ? 0 : (l - 1)];
  bool valid = false;
  int myc = 0;
  float4 myF = make_float4(0.f, 0.f, 0.f, 0.f);
  if (tid < CHUNK) {
    int j = l - 1 + tid;                     // slot tid <-> source j
    valid = (j >= 0) && (j <= r - 2);
    if (valid) {
      myc = mi[j];
      float tj = ti[j] - t_ref;
      myF = make_float4(__expf(gk0 * tj), __expf(gk1 * tj),
                        __expf(gk2 * tj), __expf(gk3 * tj));
    }
    cj[tid] = myc;
    Fj[tid] = myF;
  }
  __syncthreads();   // Fj/cj/teL/tlast staged

  if (valid) {
    float* q = &Q[tid >> 5][myc * KK];
    atomicAdd(q + 0, myF.x); atomicAdd(q + 1, myF.y);
    atomicAdd(q + 2, myF.z); atomicAdd(q + 3, myF.w);
  }
  __syncthreads();   // Q buckets complete

  // ---- phase A: chunk summary B falls out of the Q buckets (old phase1 ~free)
  float gk = (tid & 2) ? ((tid & 1) ? gk3 : gk2) : ((tid & 1) ? gk1 : gk0);
  float Bv = 0.f, t_end = 0.f;
  if (tid < STATE) {
    t_end = teL[g - g0];
    float tot = 0.f;
    #pragma unroll
    for (int q = 0; q < NSUB; ++q) tot += Q[q][tid];
    Bv = __expf(-gk * (t_end - t_ref)) * tot;
    g_chunkB[g * STATE + tid] = Bv;
  }
  if (g == 0 && tid == 0) out[0] = 0.f;   // ordered before flag[0] release below
  __syncthreads();   // every thread's publish issued (waves drain vmcnt at barrier)
  if (tid == 0) {
    __builtin_amdgcn_fence(__ATOMIC_RELEASE, "agent");
    __hip_atomic_store(&g_flag[g], DONE, __ATOMIC_RELAXED, __HIP_MEMORY_SCOPE_AGENT);
  }

  // ---- intra-super lookback (spin on <=31 predecessors' flags)
  int nloc = g - g0;
  if (tid < nloc) {
    while (__hip_atomic_load(&g_flag[g0 + tid], __ATOMIC_RELAXED,
                             __HIP_MEMORY_SCOPE_AGENT) != DONE)
      __builtin_amdgcn_s_sleep(2);
  }
  __syncthreads();
  __builtin_amdgcn_fence(__ATOMIC_ACQUIRE, "agent");

  float S = 0.f;
  if (tid < STATE) {
    #pragma unroll 4
    for (int u = 0; u < nloc; ++u)
      S += __expf(-gk * (t_ref - teL[u])) * g_chunkB[(g0 + u) * STATE + tid];
  }

  // ---- super closer publishes super summary from intra-super info only
  //      (so all supers close in parallel; no cross-super serial chain)
  bool closer = (nloc == SUP - 1) || (g == G - 1);
  if (closer) {
    if (tid < STATE)
      g_superB[sup * STATE + tid] = __expf(-gk * (t_end - t_ref)) * S + Bv;
    __syncthreads();   // block-uniform branch: legal
    if (tid == 0) {
      __builtin_amdgcn_fence(__ATOMIC_RELEASE, "agent");
      __hip_atomic_store(&g_sflag[sup], DONE, __ATOMIC_RELAXED, __HIP_MEMORY_SCOPE_AGENT);
    }
  }

  // ---- inter-super lookback (spin on <=24 super flags)
  if (tid < sup) {
    while (__hip_atomic_load(&g_sflag[tid], __ATOMIC_RELAXED,
                             __HIP_MEMORY_SCOPE_AGENT) != DONE)
      __builtin_amdgcn_s_sleep(2);
  }
  __syncthreads();
  __builtin_amdgcn_fence(__ATOMIC_ACQUIRE, "agent");

  if (tid < STATE) {
    #pragma unroll 4
    for (int s = 0; s < sup; ++s)
      S += __expf(-gk * (t_ref - tlast[s])) * g_superB[s * STATE + tid];
    // WB levels: Q[q] <- S + sum_{p<q} Q[p]
    float run = S;
    #pragma unroll
    for (int q = 0; q < NSUB; ++q) {
      float tq = Q[q][tid];
      Q[q][tid] = run;
      run += tq;
    }
  }
  __syncthreads();

  float local = 0.f;
  {
    int c_n = (e < cnt) ? mi[l + e] : 0;
    int rowb = c_n * ASTRIDE;
    const float4* wb = (const float4*)&Q[e >> 5][0];   // wave-uniform row
    float4 acc = make_float4(0.f, 0.f, 0.f, 0.f);
    if (e < cnt) {
      // prefix contraction over marks: h=0 -> m 0..24, h=1 -> m 25..49
      int mlo = h * 25, mhi = mlo + 25;
      #pragma unroll 5
      for (int m = mlo; m < mhi; ++m) {
        unsigned p0 = P0[rowb + m];
        unsigned p1 = P1[rowb + m];
        float4 w = wb[m];
        acc.x += __uint_as_float(p0 << 16)         * w.x;
        acc.y += __uint_as_float(p0 & 0xffff0000u) * w.y;
        acc.z += __uint_as_float(p1 << 16)         * w.z;
        acc.w += __uint_as_float(p1 & 0xffff0000u) * w.w;
      }
      // intra-sub-chunk pairwise, interleaved even/odd slots (<=16 steps each)
      #pragma unroll 4
      for (int s = (e & ~(SUBSZ - 1)) + h; s <= e; s += 2) {
        unsigned p0 = P0[rowb + cj[s]];
        unsigned p1 = P1[rowb + cj[s]];
        float4 f = Fj[s];
        acc.x += __uint_as_float(p0 << 16)         * f.x;
        acc.y += __uint_as_float(p0 & 0xffff0000u) * f.y;
        acc.z += __uint_as_float(p1 << 16)         * f.z;
        acc.w += __uint_as_float(p1 & 0xffff0000u) * f.w;
      }
    }
    // combine halves (adjacent lanes), h=0 finishes
    acc.x += __shfl_xor(acc.x, 1, 64);
    acc.y += __shfl_xor(acc.y, 1, 64);
    acc.z += __shfl_xor(acc.z, 1, 64);
    acc.w += __shfl_xor(acc.w, 1, 64);
    if (h == 0 && e < cnt) {
      float tn = ti[l + e] - t_ref;
      float lam = mu[l + e]
                + __expf(-gk0 * tn) * acc.x + __expf(-gk1 * tn) * acc.y
                + __expf(-gk2 * tn) * acc.z + __expf(-gk3 * tn) * acc.w;
      local = __logf(lam);
    }
  }
  // wave-level shuffle reduction, then 8-way LDS combine
  #pragma unroll
  for (int off = 32; off > 0; off >>= 1)
    local += __shfl_down(local, off, 64);
  if ((tid & 63) == 0) red8[tid >> 6] = local;
  __syncthreads();
  if (tid == 0) {
    float acc8 = 0.f;
    #pragma unroll
    for (int w = 0; w < 8; ++w) acc8 += red8[w];
    atomicAdd(out, acc8);
  }
}

extern "C" void kernel_launch(void* const* d_in, const int* in_sizes, int n_in,
                              void* d_out, int out_size, void* d_ws, size_t ws_size,
                              hipStream_t stream) {
  const float* ti    = (const float*)d_in[0];
  const int*   mi    = (const int*)d_in[1];
  const float* mu    = (const float*)d_in[2];
  const float* alpha = (const float*)d_in[3];
  const float* gamma = (const float*)d_in[4];
  float* out = (float*)d_out;
  int N = in_sizes[0];
  int G = (N + CHUNK - 1) / CHUNK;
  if (G > GMAX) return;   // problem is fixed at N=200000 (G=782); guard OOB

  hawkes_fused<<<G, 512, 0, stream>>>(ti, mi, mu, alpha, gamma, out, N, G);
}

// Round 2
// 96.269 us; speedup vs baseline: 1.9840x; 1.9840x over previous
//
#include <hip/hip_runtime.h>

#define CHUNK 256
#define MM 50
#define KK 4
#define STATE (MM*KK)   // 200
#define ASTRIDE 51      // odd word stride for P0/P1 rows (full 32-bank spread)
#define SUP 32          // chunks per super-chunk
#define NSMAX 26        // max super-chunks (G<=832)
#define NSUB 8          // sub-chunks per chunk
#define SUBSZ 32        // events per sub-chunk
#define GMAX 1024

// Cross-block communication lives in device globals (.bss -> zeroed at module
// load). Flags are epoch-valued (DONE = ticket/G + 1), so repeated graph
// replays stay correct with NO per-iteration reset and NO init dispatch.
// ALL cross-block data moves via per-access agent-scope atomics (sc1: bypass
// the non-coherent per-XCD L2, hit MALL directly). NO agent fences -- those
// lower to bulk buffer_wbl2/buffer_inv and cost ~100us/dispatch (round-1 PM).
__device__ int      g_ticket;               // monotone across iterations
__device__ unsigned g_flag[GMAX];           // chunk-done flags
__device__ unsigned g_sflag[64];            // super-done flags
__device__ float    g_chunkB[GMAX * STATE];
__device__ float    g_superB[64 * STATE];

__device__ __forceinline__ unsigned short f2bf(float x) {
  unsigned u = __float_as_uint(x);
  u += 0x7fffu + ((u >> 16) & 1u);   // round-to-nearest-even
  return (unsigned short)(u >> 16);
}

__device__ __forceinline__ void st_agent(float* p, float v) {
  __hip_atomic_store(p, v, __ATOMIC_RELAXED, __HIP_MEMORY_SCOPE_AGENT);
}
__device__ __forceinline__ float ld_agent(const float* p) {
  return __hip_atomic_load(p, __ATOMIC_RELAXED, __HIP_MEMORY_SCOPE_AGENT);
}

__global__ __launch_bounds__(512) void hawkes_fused(
    const float* __restrict__ ti, const int* __restrict__ mi,
    const float* __restrict__ mu, const float* __restrict__ alpha,
    const float* __restrict__ gamma, float* __restrict__ out, int N, int G) {
  int tid = threadIdx.x;
  __shared__ int vid_s;
  __shared__ unsigned P0[MM * ASTRIDE];          // bf16x2 {k0,k1} of gamma_k*alpha
  __shared__ unsigned P1[MM * ASTRIDE];          // bf16x2 {k2,k3}
  __shared__ __align__(16) float4 Fj[CHUNK];     // exp(+gamma_k*(t_j - t_ref))
  __shared__ int   cj[CHUNK];
  __shared__ __align__(16) float Q[NSUB][STATE]; // sub-chunk buckets -> WB prefix
  __shared__ float red8[8];
  __shared__ float teL[SUP];                     // end times of chunks g0..g0+SUP-1
  __shared__ float tlast[NSMAX];                 // end times of supers 0..sup-1

  // ticket -> virtual block id in dispatch order (deadlock-free lookback)
  if (tid == 0) vid_s = atomicAdd(&g_ticket, 1);

  float gk0 = gamma[0], gk1 = gamma[1], gk2 = gamma[2], gk3 = gamma[3];

  for (int i = tid; i < NSUB * STATE; i += 512) ((float*)Q)[i] = 0.f;

  for (int idx = tid; idx < MM * MM; idx += 512) {
    int c = idx / MM, cp = idx - c * MM;
    float a0 = gk0 * alpha[idx];
    float a1 = gk1 * alpha[2500 + idx];
    float a2 = gk2 * alpha[5000 + idx];
    float a3 = gk3 * alpha[7500 + idx];
    P0[c * ASTRIDE + cp] = (unsigned)f2bf(a0) | ((unsigned)f2bf(a1) << 16);
    P1[c * ASTRIDE + cp] = (unsigned)f2bf(a2) | ((unsigned)f2bf(a3) << 16);
  }
  __syncthreads();   // vid ready (also Q zeroed, P staged)

  int tkt = vid_s;
  int epoch = tkt / G;
  int g = tkt - epoch * G;
  unsigned DONE = (unsigned)epoch + 1u;
  int l = g * CHUNK;
  int r = min(N, l + CHUNK);
  int cnt = r - l;
  int sup = g / SUP;
  int g0 = sup * SUP;
  int e = tid >> 1;    // event slot 0..255 (wave w <-> sub-chunk w)
  int h = tid & 1;     // half: 0 = low marks/even slots, 1 = high marks/odd slots

  // stage end-times for the direct prefix sums
  if (tid < SUP) {
    int c = g0 + tid;
    if (c < G) teL[tid] = ti[min(N, (c + 1) * CHUNK) - 1];
  } else if (tid >= 64 && tid < 64 + NSMAX) {
    int s = tid - 64;
    if (s < sup) tlast[s] = ti[min(N, (s + 1) * SUP * CHUNK) - 1];
  }

  float t_ref = ti[(g == 0) ? 0 : (l - 1)];
  bool valid = false;
  int myc = 0;
  float4 myF = make_float4(0.f, 0.f, 0.f, 0.f);
  if (tid < CHUNK) {
    int j = l - 1 + tid;                     // slot tid <-> source j
    valid = (j >= 0) && (j <= r - 2);
    if (valid) {
      myc = mi[j];
      float tj = ti[j] - t_ref;
      myF = make_float4(__expf(gk0 * tj), __expf(gk1 * tj),
                        __expf(gk2 * tj), __expf(gk3 * tj));
    }
    cj[tid] = myc;
    Fj[tid] = myF;
  }
  __syncthreads();   // Fj/cj/teL/tlast staged

  if (valid) {
    float* q = &Q[tid >> 5][myc * KK];
    atomicAdd(q + 0, myF.x); atomicAdd(q + 1, myF.y);
    atomicAdd(q + 2, myF.z); atomicAdd(q + 3, myF.w);
  }
  __syncthreads();   // Q buckets complete

  // ---- phase A: chunk summary B falls out of the Q buckets
  float gk = (tid & 2) ? ((tid & 1) ? gk3 : gk2) : ((tid & 1) ? gk1 : gk0);
  float Bv = 0.f, t_end = 0.f;
  if (tid < STATE) {
    t_end = teL[g - g0];
    float tot = 0.f;
    #pragma unroll
    for (int q = 0; q < NSUB; ++q) tot += Q[q][tid];
    Bv = __expf(-gk * (t_end - t_ref)) * tot;
    st_agent(&g_chunkB[g * STATE + tid], Bv);   // sc1: straight to MALL
  }
  if (g == 0 && tid == 0) st_agent(out, 0.f);   // at MALL, same point as atomicAdds
  __syncthreads();   // all waves drain vmcnt(0) at barrier -> data visible
  if (tid == 0) {
    asm volatile("s_waitcnt vmcnt(0)" ::: "memory");
    __hip_atomic_store(&g_flag[g], DONE, __ATOMIC_RELAXED, __HIP_MEMORY_SCOPE_AGENT);
  }

  // ---- intra-super lookback (spin on <=31 predecessors' flags)
  int nloc = g - g0;
  if (tid < nloc) {
    while (__hip_atomic_load(&g_flag[g0 + tid], __ATOMIC_RELAXED,
                             __HIP_MEMORY_SCOPE_AGENT) != DONE)
      __builtin_amdgcn_s_sleep(2);
  }
  __syncthreads();   // all predecessors' data is at MALL; sc1 loads below see it

  float S = 0.f;
  if (tid < STATE) {
    #pragma unroll 4
    for (int u = 0; u < nloc; ++u)
      S += __expf(-gk * (t_ref - teL[u])) * ld_agent(&g_chunkB[(g0 + u) * STATE + tid]);
  }

  // ---- super closer publishes super summary from intra-super info only
  bool closer = (nloc == SUP - 1) || (g == G - 1);
  if (closer) {
    if (tid < STATE)
      st_agent(&g_superB[sup * STATE + tid], __expf(-gk * (t_end - t_ref)) * S + Bv);
    __syncthreads();   // block-uniform branch: legal; drains vmcnt
    if (tid == 0) {
      asm volatile("s_waitcnt vmcnt(0)" ::: "memory");
      __hip_atomic_store(&g_sflag[sup], DONE, __ATOMIC_RELAXED, __HIP_MEMORY_SCOPE_AGENT);
    }
  }

  // ---- inter-super lookback (spin on <=24 super flags)
  if (tid < sup) {
    while (__hip_atomic_load(&g_sflag[tid], __ATOMIC_RELAXED,
                             __HIP_MEMORY_SCOPE_AGENT) != DONE)
      __builtin_amdgcn_s_sleep(2);
  }
  __syncthreads();

  if (tid < STATE) {
    #pragma unroll 4
    for (int s = 0; s < sup; ++s)
      S += __expf(-gk * (t_ref - tlast[s])) * ld_agent(&g_superB[s * STATE + tid]);
    // WB levels: Q[q] <- S + sum_{p<q} Q[p]
    float run = S;
    #pragma unroll
    for (int q = 0; q < NSUB; ++q) {
      float tq = Q[q][tid];
      Q[q][tid] = run;
      run += tq;
    }
  }
  __syncthreads();

  float local = 0.f;
  {
    int c_n = (e < cnt) ? mi[l + e] : 0;
    int rowb = c_n * ASTRIDE;
    const float4* wb = (const float4*)&Q[e >> 5][0];   // wave-uniform row
    float4 acc = make_float4(0.f, 0.f, 0.f, 0.f);
    if (e < cnt) {
      // prefix contraction over marks: h=0 -> m 0..24, h=1 -> m 25..49
      int mlo = h * 25, mhi = mlo + 25;
      #pragma unroll 5
      for (int m = mlo; m < mhi; ++m) {
        unsigned p0 = P0[rowb + m];
        unsigned p1 = P1[rowb + m];
        float4 w = wb[m];
        acc.x += __uint_as_float(p0 << 16)         * w.x;
        acc.y += __uint_as_float(p0 & 0xffff0000u) * w.y;
        acc.z += __uint_as_float(p1 << 16)         * w.z;
        acc.w += __uint_as_float(p1 & 0xffff0000u) * w.w;
      }
      // intra-sub-chunk pairwise, interleaved even/odd slots (<=16 steps each)
      #pragma unroll 4
      for (int s = (e & ~(SUBSZ - 1)) + h; s <= e; s += 2) {
        unsigned p0 = P0[rowb + cj[s]];
        unsigned p1 = P1[rowb + cj[s]];
        float4 f = Fj[s];
        acc.x += __uint_as_float(p0 << 16)         * f.x;
        acc.y += __uint_as_float(p0 & 0xffff0000u) * f.y;
        acc.z += __uint_as_float(p1 << 16)         * f.z;
        acc.w += __uint_as_float(p1 & 0xffff0000u) * f.w;
      }
    }
    // combine halves (adjacent lanes), h=0 finishes
    acc.x += __shfl_xor(acc.x, 1, 64);
    acc.y += __shfl_xor(acc.y, 1, 64);
    acc.z += __shfl_xor(acc.z, 1, 64);
    acc.w += __shfl_xor(acc.w, 1, 64);
    if (h == 0 && e < cnt) {
      float tn = ti[l + e] - t_ref;
      float lam = mu[l + e]
                + __expf(-gk0 * tn) * acc.x + __expf(-gk1 * tn) * acc.y
                + __expf(-gk2 * tn) * acc.z + __expf(-gk3 * tn) * acc.w;
      local = __logf(lam);
    }
  }
  // wave-level shuffle reduction, then 8-way LDS combine
  #pragma unroll
  for (int off = 32; off > 0; off >>= 1)
    local += __shfl_down(local, off, 64);
  if ((tid & 63) == 0) red8[tid >> 6] = local;
  __syncthreads();
  if (tid == 0) {
    float acc8 = 0.f;
    #pragma unroll
    for (int w = 0; w < 8; ++w) acc8 += red8[w];
    atomicAdd(out, acc8);
  }
}

extern "C" void kernel_launch(void* const* d_in, const int* in_sizes, int n_in,
                              void* d_out, int out_size, void* d_ws, size_t ws_size,
                              hipStream_t stream) {
  const float* ti    = (const float*)d_in[0];
  const int*   mi    = (const int*)d_in[1];
  const float* mu    = (const float*)d_in[2];
  const float* alpha = (const float*)d_in[3];
  const float* gamma = (const float*)d_in[4];
  float* out = (float*)d_out;
  int N = in_sizes[0];
  int G = (N + CHUNK - 1) / CHUNK;
  if (G > GMAX) return;   // problem is fixed at N=200000 (G=782); guard OOB

  hawkes_fused<<<G, 512, 0, stream>>>(ti, mi, mu, alpha, gamma, out, N, G);
}

// Round 3
// 94.005 us; speedup vs baseline: 2.0317x; 1.0241x over previous
//
#include <hip/hip_runtime.h>

#define CHUNK 256
#define MM 50
#define KK 4
#define STATE (MM*KK)   // 200
#define ASTRIDE 51      // odd granule stride (conflict-spread for uint2 rows)
#define SUP 32          // chunks per super-chunk
#define NSMAX 26        // max super-chunks (G<=832)
#define NSUB 8          // sub-chunks per chunk
#define SUBSZ 32        // events per sub-chunk
#define GMAX 1024

// Cross-block state in .bss device globals (zeroed at load). Epoch-valued
// flags (DONE = ticket/G + 1) keep graph replays correct with no resets.
// All cross-block traffic uses per-access agent-scope atomics (sc1 -> MALL,
// bypassing non-coherent per-XCD L2). NO agent fences (bulk wbl2/inv cost
// ~100us/dispatch -- round-1 post-mortem).
__device__ int      g_ticket;
__device__ unsigned g_flag[GMAX];
__device__ unsigned g_sflag[64];
__device__ float    g_chunkB[GMAX * STATE];
__device__ float    g_superB[64 * STATE];

__device__ __forceinline__ unsigned short f2bf(float x) {
  unsigned u = __float_as_uint(x);
  u += 0x7fffu + ((u >> 16) & 1u);   // round-to-nearest-even
  return (unsigned short)(u >> 16);
}
__device__ __forceinline__ float bflo(unsigned u) { return __uint_as_float(u << 16); }
__device__ __forceinline__ float bfhi(unsigned u) { return __uint_as_float(u & 0xffff0000u); }

__device__ __forceinline__ void st_agent(float* p, float v) {
  __hip_atomic_store(p, v, __ATOMIC_RELAXED, __HIP_MEMORY_SCOPE_AGENT);
}
__device__ __forceinline__ float ld_agent(const float* p) {
  return __hip_atomic_load(p, __ATOMIC_RELAXED, __HIP_MEMORY_SCOPE_AGENT);
}

__global__ __launch_bounds__(512) void hawkes_fused(
    const float* __restrict__ ti, const int* __restrict__ mi,
    const float* __restrict__ mu, const float* __restrict__ alpha,
    const float* __restrict__ gamma, float* __restrict__ out, int N, int G) {
  int tid = threadIdx.x;
  __shared__ int vid_s;
  __shared__ uint2 P[MM * ASTRIDE];              // bf16x4 {k0,k1 | k2,k3} of gamma_k*alpha
  __shared__ __align__(16) float4 Fj[CHUNK];     // exp(+gamma_k*(t_j - t_ref))
  __shared__ int   cj[CHUNK];
  __shared__ __align__(16) float Q[NSUB][STATE]; // sub-chunk buckets -> LOCAL prefix
  __shared__ float red8[8];
  __shared__ float teL[SUP];                     // end times of chunks g0..g0+SUP-1
  __shared__ float tlast[NSMAX];                 // end times of supers 0..sup-1
  __shared__ float S_lds[STATE];                 // inter-chunk prefix state
  __shared__ __align__(16) float R_lds[MM * 20]; // R[c] as float4, row stride 5 granules

  // ticket only for the replay-epoch counter; g = blockIdx.x is safe since
  // all G<=1024 blocks are co-resident (4 blocks/CU x 256 CUs).
  if (tid == 0) vid_s = atomicAdd(&g_ticket, 1);

  int g = blockIdx.x;
  int l = g * CHUNK;
  int r = min(N, l + CHUNK);
  int cnt = r - l;
  int sup = g / SUP;
  int g0 = sup * SUP;
  int e = tid >> 1;    // event slot 0..255 (wave w <-> sub-chunk w)
  int h = tid & 1;     // half: 0 = marks 0..24, 1 = marks 25..49

  float gk0 = gamma[0], gk1 = gamma[1], gk2 = gamma[2], gk3 = gamma[3];

  for (int i = tid; i < NSUB * STATE; i += 512) ((float*)Q)[i] = 0.f;

  if (tid < SUP) {
    int c = g0 + tid;
    if (c < G) teL[tid] = ti[min(N, (c + 1) * CHUNK) - 1];
  } else if (tid >= 64 && tid < 64 + NSMAX) {
    int s = tid - 64;
    if (s < sup) tlast[s] = ti[min(N, (s + 1) * SUP * CHUNK) - 1];
  }

  float t_ref = ti[(g == 0) ? 0 : (l - 1)];
  bool valid = false;
  int myc = 0;
  float4 myF = make_float4(0.f, 0.f, 0.f, 0.f);
  if (tid < CHUNK) {
    int j = l - 1 + tid;                     // slot tid <-> source j
    valid = (j >= 0) && (j <= r - 2);
    if (valid) {
      myc = mi[j];
      float tj = ti[j] - t_ref;
      myF = make_float4(__expf(gk0 * tj), __expf(gk1 * tj),
                        __expf(gk2 * tj), __expf(gk3 * tj));
    }
    cj[tid] = myc;
    Fj[tid] = myF;
  }
  __syncthreads();   // B1: Q zeroed, Fj/cj/teL/tlast staged, vid ready

  if (valid) {
    float* q = &Q[tid >> 5][myc * KK];
    atomicAdd(q + 0, myF.x); atomicAdd(q + 1, myF.y);
    atomicAdd(q + 2, myF.z); atomicAdd(q + 3, myF.w);
  }
  __syncthreads();   // B2: Q buckets complete

  // ---- chunk summary from Q buckets + LOCAL-only prefix transform
  float gk = (tid & 2) ? ((tid & 1) ? gk3 : gk2) : ((tid & 1) ? gk1 : gk0);
  float Bv = 0.f, t_end = 0.f;
  if (tid < STATE) {
    t_end = teL[g - g0];
    float tot = 0.f;
    #pragma unroll
    for (int q = 0; q < NSUB; ++q) tot += Q[q][tid];
    Bv = __expf(-gk * (t_end - t_ref)) * tot;
    st_agent(&g_chunkB[g * STATE + tid], Bv);   // sc1: straight to MALL
    // local exclusive prefix (starts at 0 -- S is folded in later via R)
    float run = 0.f;
    #pragma unroll
    for (int q = 0; q < NSUB; ++q) {
      float tq = Q[q][tid];
      Q[q][tid] = run;
      run += tq;
    }
  }
  if (g == 0 && tid == 0) st_agent(out, 0.f);

  // P staging (all threads; overlaps the B/WB work above on other lanes)
  for (int idx = tid; idx < MM * MM; idx += 512) {
    int c = idx / MM, cp = idx - c * MM;
    float a0 = gk0 * alpha[idx];
    float a1 = gk1 * alpha[2500 + idx];
    float a2 = gk2 * alpha[5000 + idx];
    float a3 = gk3 * alpha[7500 + idx];
    P[c * ASTRIDE + cp] =
        make_uint2((unsigned)f2bf(a0) | ((unsigned)f2bf(a1) << 16),
                   (unsigned)f2bf(a2) | ((unsigned)f2bf(a3) << 16));
  }
  __syncthreads();   // B3: Q local-prefixed, P staged, chunkB stores drained
                     // (each wave's vmcnt(0) is drained at the barrier)
  unsigned DONE = (unsigned)(vid_s / G) + 1u;
  if (tid == 0) {
    asm volatile("s_waitcnt vmcnt(0)" ::: "memory");
    __hip_atomic_store(&g_flag[g], DONE, __ATOMIC_RELAXED, __HIP_MEMORY_SCOPE_AGENT);
  }

  int nloc = g - g0;
  bool closer = (nloc == SUP - 1) || (g == G - 1);
  float S = 0.f;

  // ---- closers: spin + intra-super gather + superB publish BEFORE the
  //      contraction, so sflags are up while everyone else is computing
  if (closer) {
    if (tid < nloc) {
      while (__hip_atomic_load(&g_flag[g0 + tid], __ATOMIC_RELAXED,
                               __HIP_MEMORY_SCOPE_AGENT) != DONE)
        __builtin_amdgcn_s_sleep(2);
    }
    __syncthreads();
    if (tid < STATE) {
      #pragma unroll 8
      for (int u = 0; u < nloc; ++u)
        S += __expf(-gk * (t_ref - teL[u])) * ld_agent(&g_chunkB[(g0 + u) * STATE + tid]);
      st_agent(&g_superB[sup * STATE + tid], __expf(-gk * (t_end - t_ref)) * S + Bv);
    }
    __syncthreads();   // drains superB stores
    if (tid == 0) {
      asm volatile("s_waitcnt vmcnt(0)" ::: "memory");
      __hip_atomic_store(&g_sflag[sup], DONE, __ATOMIC_RELAXED, __HIP_MEMORY_SCOPE_AGENT);
    }
  }

  // ---- LOCAL contraction (independent of lookback: overlaps the sync)
  int c_n = (e < cnt) ? mi[l + e] : 0;
  int rowb = c_n * ASTRIDE;
  float tn = 0.f, mun = 0.f;
  if (h == 0 && e < cnt) { tn = ti[l + e] - t_ref; mun = mu[l + e]; }
  float4 acc = make_float4(0.f, 0.f, 0.f, 0.f);
  if (e < cnt) {
    const float4* wb = (const float4*)&Q[e >> 5][0];   // wave-uniform row
    if (e >= SUBSZ) {   // sub-chunk 0 has wb == 0: skip (wave-uniform branch)
      int mlo = h * 25, mhi = mlo + 25;
      #pragma unroll 5
      for (int m = mlo; m < mhi; ++m) {
        uint2 p = P[rowb + m];
        float4 w = wb[m];
        acc.x += bflo(p.x) * w.x; acc.y += bfhi(p.x) * w.y;
        acc.z += bflo(p.y) * w.z; acc.w += bfhi(p.y) * w.w;
      }
    }
    // intra-sub-chunk pairwise, interleaved even/odd slots (<=16 steps each)
    #pragma unroll 4
    for (int s = (e & ~(SUBSZ - 1)) + h; s <= e; s += 2) {
      uint2 p = P[rowb + cj[s]];
      float4 f = Fj[s];
      acc.x += bflo(p.x) * f.x; acc.y += bfhi(p.x) * f.y;
      acc.z += bflo(p.y) * f.z; acc.w += bfhi(p.y) * f.w;
    }
  }
  acc.x += __shfl_xor(acc.x, 1, 64);
  acc.y += __shfl_xor(acc.y, 1, 64);
  acc.z += __shfl_xor(acc.z, 1, 64);
  acc.w += __shfl_xor(acc.w, 1, 64);

  // ---- tail: sync results (flags long up by now -> spins ~instant)
  if (!closer) {
    if (tid < nloc) {
      while (__hip_atomic_load(&g_flag[g0 + tid], __ATOMIC_RELAXED,
                               __HIP_MEMORY_SCOPE_AGENT) != DONE)
        __builtin_amdgcn_s_sleep(2);
    }
    __syncthreads();
    if (tid < STATE) {
      #pragma unroll 8
      for (int u = 0; u < nloc; ++u)
        S += __expf(-gk * (t_ref - teL[u])) * ld_agent(&g_chunkB[(g0 + u) * STATE + tid]);
    }
  }
  if (tid < sup) {
    while (__hip_atomic_load(&g_sflag[tid], __ATOMIC_RELAXED,
                             __HIP_MEMORY_SCOPE_AGENT) != DONE)
      __builtin_amdgcn_s_sleep(2);
  }
  __syncthreads();
  if (tid < STATE) {
    #pragma unroll 8
    for (int s = 0; s < sup; ++s)
      S += __expf(-gk * (t_ref - tlast[s])) * ld_agent(&g_superB[s * STATE + tid]);
    S_lds[tid] = S;
  }
  __syncthreads();

  // ---- tiny matvec: R[c][k] = sum_m P[c][m][k] * S[m][k]  (10K MACs total)
  if (tid < STATE) {
    int c = tid >> 2, k = tid & 3;
    float rv = 0.f;
    #pragma unroll 5
    for (int m = 0; m < MM; ++m) {
      uint2 p = P[c * ASTRIDE + m];
      unsigned w = (k & 2) ? p.y : p.x;
      float pv = (k & 1) ? bfhi(w) : bflo(w);
      rv += pv * S_lds[m * KK + k];
    }
    R_lds[c * 20 + k] = rv;
  }
  __syncthreads();

  // ---- finalize lambda and reduce
  float local = 0.f;
  if (h == 0 && e < cnt) {
    float4 rv = *(const float4*)&R_lds[c_n * 20];
    float lam = mun
              + __expf(-gk0 * tn) * (acc.x + rv.x)
              + __expf(-gk1 * tn) * (acc.y + rv.y)
              + __expf(-gk2 * tn) * (acc.z + rv.z)
              + __expf(-gk3 * tn) * (acc.w + rv.w);
    local = __logf(lam);
  }
  #pragma unroll
  for (int off = 32; off > 0; off >>= 1)
    local += __shfl_down(local, off, 64);
  if ((tid & 63) == 0) red8[tid >> 6] = local;
  __syncthreads();
  if (tid == 0) {
    float acc8 = 0.f;
    #pragma unroll
    for (int w = 0; w < 8; ++w) acc8 += red8[w];
    atomicAdd(out, acc8);
  }
}

extern "C" void kernel_launch(void* const* d_in, const int* in_sizes, int n_in,
                              void* d_out, int out_size, void* d_ws, size_t ws_size,
                              hipStream_t stream) {
  const float* ti    = (const float*)d_in[0];
  const int*   mi    = (const int*)d_in[1];
  const float* mu    = (const float*)d_in[2];
  const float* alpha = (const float*)d_in[3];
  const float* gamma = (const float*)d_in[4];
  float* out = (float*)d_out;
  int N = in_sizes[0];
  int G = (N + CHUNK - 1) / CHUNK;
  if (G > GMAX) return;   // problem is fixed at N=200000 (G=782); guard OOB

  hawkes_fused<<<G, 512, 0, stream>>>(ti, mi, mu, alpha, gamma, out, N, G);
}

// Round 5
// 88.695 us; speedup vs baseline: 2.1534x; 1.0599x over previous
//
#include <hip/hip_runtime.h>

#define CHUNK 256
#define MM 50
#define KK 4
#define STATE (MM*KK)   // 200
#define ASTRIDE 51      // odd granule stride (conflict-spread for uint2 rows)
#define SUP 32          // chunks per super-chunk
#define NSMAX 26        // max super-chunks (G<=832)
#define SUBSZ 32        // events per sub-chunk
#define GMAX 1024

// Cross-block state in .bss device globals (zeroed at load). Epoch-valued
// flags (DONE = ticket/NB + 1) keep graph replays correct with no resets.
// All cross-block traffic uses per-access agent-scope atomics (sc1 -> MALL,
// bypassing non-coherent per-XCD L2). NO agent fences (bulk wbl2/inv cost
// ~100us/dispatch -- round-1 post-mortem).
__device__ int      g_ticket;
__device__ unsigned g_flag[GMAX];
__device__ unsigned g_sflag[64];
__device__ float    g_chunkB[GMAX * STATE];
__device__ float    g_superB[64 * STATE];

__device__ __forceinline__ unsigned short f2bf(float x) {
  unsigned u = __float_as_uint(x);
  u += 0x7fffu + ((u >> 16) & 1u);   // round-to-nearest-even
  return (unsigned short)(u >> 16);
}
__device__ __forceinline__ float bflo(unsigned u) { return __uint_as_float(u << 16); }
__device__ __forceinline__ float bfhi(unsigned u) { return __uint_as_float(u & 0xffff0000u); }

__device__ __forceinline__ void st_agent(float* p, float v) {
  __hip_atomic_store(p, v, __ATOMIC_RELAXED, __HIP_MEMORY_SCOPE_AGENT);
}
__device__ __forceinline__ float ld_agent(const float* p) {
  return __hip_atomic_load(p, __ATOMIC_RELAXED, __HIP_MEMORY_SCOPE_AGENT);
}
__device__ __forceinline__ void spin_flag(unsigned* p, unsigned want) {
  while (__hip_atomic_load(p, __ATOMIC_RELAXED, __HIP_MEMORY_SCOPE_AGENT) != want)
    __builtin_amdgcn_s_sleep(2);
}

// Block b owns chunks gA=2b, gB=2b+1. tid<256: chunk A (event tid).
// tid>=256: chunk B (event tid-256). Key identity: t_ref(B) = te(A), so
// S_B = dA*S_A + Bv_A -- chunk B needs NO extra cross-block gathers.
__global__ __launch_bounds__(512) void hawkes_fused(
    const float* __restrict__ ti, const int* __restrict__ mi,
    const float* __restrict__ mu, const float* __restrict__ alpha,
    const float* __restrict__ gamma, float* __restrict__ out,
    int N, int G, int NB) {
  int tid = threadIdx.x;
  __shared__ int vid_s;
  __shared__ uint2 P[MM * ASTRIDE];              // bf16x4 {k0,k1 | k2,k3} of gamma_k*alpha
  __shared__ __align__(16) float4 Fj[2 * CHUNK]; // exp(+gk*(t_j - t_ref)), slot = tid
  __shared__ int   cj[2 * CHUNK];
  __shared__ __align__(16) float Q[16][STATE];   // levels: 0..7 chunk A, 8..15 chunk B
  __shared__ float red8[8];
  __shared__ float teL[SUP];                     // end times of chunks g0c..g0c+31
  __shared__ float tlast[NSMAX];                 // end times of supers 0..sup-1
  __shared__ float SldsA[STATE];
  __shared__ float SldsB[STATE];                 // also closer temp
  __shared__ __align__(16) float RA[MM * 20];    // R[c] float4, row stride 5 granules
  __shared__ __align__(16) float RB[MM * 20];

  if (tid == 0) vid_s = atomicAdd(&g_ticket, 1);

  int b = blockIdx.x;
  int gA = 2 * b, gB = gA + 1;
  bool hasB = (gB < G);
  int lA = gA * CHUNK;
  int sup = gA / SUP;
  int g0c = sup * SUP;
  int half = tid >> 8;     // 0 = chunk A, 1 = chunk B (wave-uniform)
  int cidx = tid & 255;

  float gk0 = gamma[0], gk1 = gamma[1], gk2 = gamma[2], gk3 = gamma[3];
  float gkc = (tid & 2) ? ((tid & 1) ? gk3 : gk2) : ((tid & 1) ? gk1 : gk0);

  for (int i = tid; i < 16 * STATE; i += 512) ((float*)Q)[i] = 0.f;

  if (tid < SUP) {
    int c = g0c + tid;
    if (c < G) teL[tid] = ti[min(N, (c + 1) * CHUNK) - 1];
  } else if (tid >= 64 && tid < 64 + NSMAX) {
    int s = tid - 64;
    if (s < sup) tlast[s] = ti[min(N, (s + 1) * SUP * CHUNK) - 1];
  }

  float t_refA = ti[(gA == 0) ? 0 : (lA - 1)];
  float t_refB = ti[min(N, lA + CHUNK) - 1];   // = te(A) when chunk B exists
  float t_ref = half ? t_refB : t_refA;

  // stage both chunks' events in one pass (slot = tid, source j = lA-1+tid)
  int j = lA - 1 + tid;
  int rX = min(N, lA + (half + 1) * CHUNK);
  bool valid = (j >= 0) && (j <= rX - 2);
  int myc = 0;
  float4 myF = make_float4(0.f, 0.f, 0.f, 0.f);
  if (valid) {
    myc = mi[j];
    float tj = ti[j] - t_ref;
    myF = make_float4(__expf(gk0 * tj), __expf(gk1 * tj),
                      __expf(gk2 * tj), __expf(gk3 * tj));
  }
  cj[tid] = myc;
  Fj[tid] = myF;
  __syncthreads();   // B1: Q zeroed, staging done, teL/tlast/vid ready

  if (valid) {
    float* q = &Q[tid >> 5][myc * KK];
    atomicAdd(q + 0, myF.x); atomicAdd(q + 1, myF.y);
    atomicAdd(q + 2, myF.z); atomicAdd(q + 3, myF.w);
  }
  __syncthreads();   // B2: all 16 bucket levels complete

  // ---- per-chunk summaries in parallel thread groups (A: tid<200, B: 256..455)
  bool sumr = (cidx < STATE) && (half == 0 || hasB);
  int gX = half ? gB : gA;
  float Bv = 0.f, dX = 0.f;
  if (sumr) {
    float tot = 0.f;
    #pragma unroll
    for (int q = 0; q < 8; ++q) tot += Q[half * 8 + q][cidx];
    dX = __expf(-gkc * (teL[gX - g0c] - t_ref));
    Bv = dX * tot;
    st_agent(&g_chunkB[(size_t)gX * STATE + cidx], Bv);
    // local exclusive prefix over own 8 levels (starts at 0; S folded via R)
    float run = 0.f;
    #pragma unroll
    for (int q = 0; q < 8; ++q) {
      float tq = Q[half * 8 + q][cidx];
      Q[half * 8 + q][cidx] = run;
      run += tq;
    }
  }
  if (b == 0 && tid == 0) st_agent(out, 0.f);
  __syncthreads();   // B3: chunkB stores issued by all waves, drained at barrier
  unsigned DONE = (unsigned)(vid_s / NB) + 1u;
  if (tid == 0) {
    asm volatile("s_waitcnt vmcnt(0)" ::: "memory");
    __hip_atomic_store(&g_flag[gA], DONE, __ATOMIC_RELAXED, __HIP_MEMORY_SCOPE_AGENT);
    if (hasB)
      __hip_atomic_store(&g_flag[gB], DONE, __ATOMIC_RELAXED, __HIP_MEMORY_SCOPE_AGENT);
  }

  // P staging (off the flag critical path now)
  for (int idx = tid; idx < MM * MM; idx += 512) {
    int c = idx / MM, cp = idx - c * MM;
    float a0 = gk0 * alpha[idx];
    float a1 = gk1 * alpha[2500 + idx];
    float a2 = gk2 * alpha[5000 + idx];
    float a3 = gk3 * alpha[7500 + idx];
    P[c * ASTRIDE + cp] =
        make_uint2((unsigned)f2bf(a0) | ((unsigned)f2bf(a1) << 16),
                   (unsigned)f2bf(a2) | ((unsigned)f2bf(a3) << 16));
  }

  // prefetch per-event finals (n = lA + tid works for both halves)
  int n = lA + tid;
  bool en = (n < N);
  int c_n = en ? mi[n] : 0;
  float tn = 0.f, mun = 0.f;
  if (en) { tn = ti[n] - t_ref; mun = mu[n]; }

  int nlocA = gA - g0c;   // even, <= 30
  bool closer = (hasB && (gB - g0c == SUP - 1)) || (b == NB - 1);
  float S = 0.f;

  // ---- closers: early spin + intra gather + superB publish (before contraction)
  if (closer) {
    if (tid < nlocA) spin_flag(&g_flag[g0c + tid], DONE);
    __syncthreads();
    if (tid < STATE) {
      #pragma unroll 16
      for (int u = 0; u < nlocA; ++u)
        S += __expf(-gkc * (t_refA - teL[u])) * ld_agent(&g_chunkB[(size_t)(g0c + u) * STATE + tid]);
      SldsB[tid] = dX * S + Bv;   // temp: intra prefix incl chunk A, anchored t_refB
    }
    __syncthreads();
    if (sumr && half) {           // tid 256..455 hold chunk-B dX/Bv
      st_agent(&g_superB[(size_t)sup * STATE + cidx], dX * SldsB[cidx] + Bv);
    }
    __syncthreads();
    if (tid == 0) {
      asm volatile("s_waitcnt vmcnt(0)" ::: "memory");
      __hip_atomic_store(&g_sflag[sup], DONE, __ATOMIC_RELAXED, __HIP_MEMORY_SCOPE_AGENT);
    }
  }
  __syncthreads();   // B4: P staged; contraction may read it

  // ---- contraction: 1 thread/event, both chunks concurrently on separate waves
  float4 acc = make_float4(0.f, 0.f, 0.f, 0.f);
  if (en) {
    int rowb = c_n * ASTRIDE;
    const float4* wb = (const float4*)&Q[tid >> 5][0];
    if (cidx >= SUBSZ) {   // sub-chunk 0 of each half has wb == 0
      #pragma unroll 10
      for (int m = 0; m < MM; ++m) {
        uint2 p = P[rowb + m];
        float4 w = wb[m];
        acc.x += bflo(p.x) * w.x; acc.y += bfhi(p.x) * w.y;
        acc.z += bflo(p.y) * w.z; acc.w += bfhi(p.y) * w.w;
      }
    }
    int base = tid & ~(SUBSZ - 1);
    #pragma unroll 4
    for (int s = base; s <= tid; ++s) {
      uint2 p = P[rowb + cj[s]];
      float4 f = Fj[s];
      acc.x += bflo(p.x) * f.x; acc.y += bfhi(p.x) * f.y;
      acc.z += bflo(p.y) * f.z; acc.w += bfhi(p.y) * f.w;
    }
  }

  // ---- tail: gather S_A (flags long up), derive S_B for free
  if (!closer) {
    if (tid < nlocA) spin_flag(&g_flag[g0c + tid], DONE);
    __syncthreads();
    if (tid < STATE) {
      #pragma unroll 16
      for (int u = 0; u < nlocA; ++u)
        S += __expf(-gkc * (t_refA - teL[u])) * ld_agent(&g_chunkB[(size_t)(g0c + u) * STATE + tid]);
    }
  }
  if (tid < sup) spin_flag(&g_sflag[tid], DONE);
  __syncthreads();
  if (tid < STATE) {
    #pragma unroll 16
    for (int s = 0; s < sup; ++s)
      S += __expf(-gkc * (t_refA - tlast[s])) * ld_agent(&g_superB[(size_t)s * STATE + tid]);
    SldsA[tid] = S;
    SldsB[tid] = dX * S + Bv;    // S_B = dA*S_A + Bv_A (t_refB == te_A)
  }
  __syncthreads();

  // ---- matvecs R[c][k] = sum_m P[c][m][k]*S[m][k], A and B in parallel groups
  if (sumr) {
    int c = cidx >> 2, k = cidx & 3;
    const float* Sx = half ? SldsB : SldsA;
    float rv = 0.f;
    #pragma unroll 10
    for (int m = 0; m < MM; ++m) {
      uint2 p = P[c * ASTRIDE + m];
      unsigned w = (k & 2) ? p.y : p.x;
      float pv = (k & 1) ? bfhi(w) : bflo(w);
      rv += pv * Sx[m * KK + k];
    }
    (half ? RB : RA)[c * 20 + k] = rv;
  }
  __syncthreads();

  // ---- finalize lambda and reduce
  float local = 0.f;
  if (en) {
    const float* Rx = half ? RB : RA;
    float4 rv = *(const float4*)&Rx[c_n * 20];
    float lam = mun
              + __expf(-gk0 * tn) * (acc.x + rv.x)
              + __expf(-gk1 * tn) * (acc.y + rv.y)
              + __expf(-gk2 * tn) * (acc.z + rv.z)
              + __expf(-gk3 * tn) * (acc.w + rv.w);
    local = __logf(lam);
  }
  #pragma unroll
  for (int off = 32; off > 0; off >>= 1)
    local += __shfl_down(local, off, 64);
  if ((tid & 63) == 0) red8[tid >> 6] = local;
  __syncthreads();
  if (tid == 0) {
    float acc8 = 0.f;
    #pragma unroll
    for (int w = 0; w < 8; ++w) acc8 += red8[w];
    atomicAdd(out, acc8);
  }
}

extern "C" void kernel_launch(void* const* d_in, const int* in_sizes, int n_in,
                              void* d_out, int out_size, void* d_ws, size_t ws_size,
                              hipStream_t stream) {
  const float* ti    = (const float*)d_in[0];
  const int*   mi    = (const int*)d_in[1];
  const float* mu    = (const float*)d_in[2];
  const float* alpha = (const float*)d_in[3];
  const float* gamma = (const float*)d_in[4];
  float* out = (float*)d_out;
  int N = in_sizes[0];
  int G = (N + CHUNK - 1) / CHUNK;
  if (G > GMAX) return;   // problem is fixed at N=200000 (G=782); guard OOB
  int NB = (G + 1) / 2;

  hawkes_fused<<<NB, 512, 0, stream>>>(ti, mi, mu, alpha, gamma, out, N, G, NB);
}